// Round 6
// baseline (128.080 us; speedup 1.0000x reference)
//
#include <hip/hip_runtime.h>
#include <hip/hip_fp16.h>

// Radon forward: x [4,1,256,256] f32, thetas[180], positions[256] -> out [4,1,180,256] f32
// T=363 samples/ray (we run 364; the extra one lands in the zero border -> +0).
//
// Occupancy fix: each block stages HALF the image (~69KB) -> 2 blocks/CU, 32 waves/CU.
// Split axis per angle regime: row-split when |cos|>=0.707 (a<45 or a>=135),
// col-split when |sin|>=0.707 (45<=a<135). Each half-block owns a contiguous
// t-subrange computed from the identical float expression in both halves
// (exact partition); 1-row/col staging slack absorbs boundary rounding.
// Halves combine via atomicAdd (2 adds/output: order-independent bit-exact).

#define NB   4
#define NA   180
#define NP   256
#define GANG 3       // angles per block; regime boundaries 45,135 are multiples of 3
#define NSEG 4

// Regime A (row-split): stride 131 dw (262 halves), 132 alloc rows -> 17292 dw
// Regime B (col-split): stride  67 dw (134 halves), 259 alloc rows -> 17353 dw
#define IMG_DW_MAX 17353
#define RED_OFF ((IMG_DW_MAX + 1) * 4)        // 69416 (pad 1 dw: benign tap-read slack)
#define SMEM_BYTES (RED_OFF + NP * NSEG * 4)  // 73512 ; 2 blocks = 147KB <= 160KB/CU

template<int STRIDE_DW>
__device__ __forceinline__ float ray_accum(
    const unsigned int* __restrict__ imgw,
    float bxr, float byr, float nsv, float cv,
    float xlo, float xhi, float ylo, float yhi,
    int tlo, int thi, int seg)
{
    float acc = 0.f;
    int   t  = tlo + seg;
    float tf = (float)t - 181.0f;          // (T-1)/2
    #pragma unroll 4
    for (; t < thi; t += 4, tf += 4.0f) {
        float px = fmaf(tf, nsv, bxr);
        float py = fmaf(tf, cv,  byr);
        px = __builtin_amdgcn_fmed3f(px, xlo, xhi);   // clamp into staged+zero region
        py = __builtin_amdgcn_fmed3f(py, ylo, yhi);
        const float fx = floorf(px);
        const float fy = floorf(py);
        const float wx = px - fx;
        const float wy = py - fy;
        const int a = (int)fmaf(fy, (float)(2 * STRIDE_DW), fx);  // half-index
        const int kd = a >> 1;
        const unsigned sh = (a & 1) << 4;
        const unsigned d0 = imgw[kd];
        const unsigned d1 = imgw[kd + 1];
        const unsigned d2 = imgw[kd + STRIDE_DW];
        const unsigned d3 = imgw[kd + STRIDE_DW + 1];
        unsigned q0 = (unsigned)(((((unsigned long long)d1) << 32) | d0) >> sh);
        unsigned q1 = (unsigned)(((((unsigned long long)d3) << 32) | d2) >> sh);
        const __half2 h0 = *reinterpret_cast<__half2*>(&q0);   // (v00, v01)
        const __half2 h1 = *reinterpret_cast<__half2*>(&q1);   // (v10, v11)
        // vertical lerp packed in f16, horizontal in f32
        const __half2 dv  = __hsub2(h1, h0);
        const __half2 wy2 = __half2half2(__float2half_rn(wy));
        const __half2 V   = __hfma2(wy2, dv, h0);
        const float vlo = __half2float(__low2half(V));
        const float vhi = __half2float(__high2half(V));
        acc = fmaf(wx, vhi - vlo, acc + vlo);
    }
    return acc;
}

extern "C" __global__ __launch_bounds__(1024)
void radon_fwd(const float* __restrict__ x,
               const float* __restrict__ thetas,
               const float* __restrict__ positions,
               float* __restrict__ out)
{
    extern __shared__ unsigned char smem[];
    unsigned int* imgw = (unsigned int*)smem;
    __half2*      img2 = (__half2*)smem;
    float*        red  = (float*)(smem + RED_OFF);

    const int grp  = blockIdx.x;
    const int b    = blockIdx.y;
    const int half = blockIdx.z;
    const int a0   = grp * GANG;
    const bool regA = (a0 < 45) || (a0 >= 135);
    const int tid = threadIdx.x + (threadIdx.y << 8);
    const float* __restrict__ xb = x + b * 65536;

    // --- zero LDS image area ---
    for (int i = tid; i <= IMG_DW_MAX; i += 1024) imgw[i] = 0u;
    __syncthreads();

    // --- stage half image as f16 (zero border built in) ---
    if (regA) {
        // half0: img rows 0..129 -> lds rows 1..130 ; half1: img rows 126..255 -> lds rows 0..129
        const int rbase  = half ? 126 : 0;
        const int rowoff = half ? 0 : 1;
        const float2* src2 = (const float2*)(xb + rbase * 256);
        for (int j = tid; j < 130 * 128; j += 1024) {
            const int rr = j >> 7;         // 0..129
            const int k  = j & 127;        // float2 index within row (128 per row)
            float2 v = src2[rr * 128 + k];
            img2[(rr + rowoff) * 131 + k + 1] = __floats2half2_rn(v.x, v.y);
        }
    } else {
        // half0: img cols 0..131 -> lds dw cols 1..66 ; half1: img cols 124..255 -> dw cols 0..65
        const int cbase2 = half ? 62 : 0;
        const int coff   = half ? 0 : 1;
        const float2* src2 = (const float2*)xb;
        for (int rr = tid >> 6; rr < 256; rr += 16) {
            for (int c2 = tid & 63; c2 < 66; c2 += 64) {
                float2 v = src2[rr * 128 + cbase2 + c2];
                img2[(rr + 1) * 67 + c2 + coff] = __floats2half2_rn(v.x, v.y);
            }
        }
    }
    __syncthreads();

    // --- per-half clamp bounds (alloc space, rebased) ---
    float xlo, xhi, ylo, yhi;
    if (regA) {
        xlo = 1.f; xhi = 258.f;
        if (half == 0) { ylo = 0.f; yhi = 129.984375f; }
        else           { ylo = 1.f; yhi = 130.f; }
    } else {
        ylo = 0.f; yhi = 257.f;
        if (half == 0) { xlo = 1.f; xhi = 130.984375f; }
        else           { xlo = 3.f; xhi = 132.f; }
    }
    const float rebY = (regA && half) ? 127.f : 0.f;
    const float rebX = (!regA && half) ? 126.f : 0.f;

    const int   p   = threadIdx.x;
    const int   seg = threadIdx.y;
    const float s   = positions[p];

    float accs[GANG];
    for (int g = 0; g < GANG; ++g) {
        const float th  = thetas[a0 + g];
        const float cv  = cosf(th);
        const float sv  = sinf(th);
        const float nsv = -sv;
        const float bx2 = fmaf(s, cv, 129.5f);   // alloc-x base (col offset +2)
        const float by1 = fmaf(s, sv, 128.5f);   // alloc-y base (row offset +1)
        // ownership split -- IDENTICAL float computation in both halves.
        // alloc(t) = base + (t - 181)*slope  =>  t* = 181 + (thr - base)/slope
        // (round-4/5 bug: the 181 re-centering was missing -> split off by 181 samples)
        const float slope = regA ? cv : nsv;     // |slope| >= 0.707 by regime choice
        const float base  = regA ? by1 : bx2;
        const float thr   = regA ? 129.f : 130.f;
        const float tstar = 181.0f + (thr - base) / slope;
        const float Sf    = (slope > 0.f) ? ceilf(tstar) : (floorf(tstar) + 1.0f);
        const int   S     = (int)fmaxf(0.f, fminf(364.f, Sf));
        const bool  h0Low = (slope > 0.f);       // half0 owns low-t side iff slope>0
        int lo, hi;
        if ((half == 0) == h0Low) { lo = 0; hi = S; }
        else                      { lo = S; hi = 364; }
        const float bxr = bx2 - rebX;
        const float byr = by1 - rebY;
        accs[g] = regA
            ? ray_accum<131>(imgw, bxr, byr, nsv, cv, xlo, xhi, ylo, yhi, lo, hi, seg)
            : ray_accum< 67>(imgw, bxr, byr, nsv, cv, xlo, xhi, ylo, yhi, lo, hi, seg);
    }

    // --- reduce 4 segs, then one atomicAdd per (g,p) (2 adds/output total) ---
    for (int g = 0; g < GANG; ++g) {
        __syncthreads();
        red[(seg << 8) + p] = accs[g];
        __syncthreads();
        if (seg == 0) {
            float r4 = red[p] + red[256 + p] + red[512 + p] + red[768 + p];
            atomicAdd(&out[b * (NA * NP) + (a0 + g) * NP + p], r4);
        }
    }
}

extern "C" void kernel_launch(void* const* d_in, const int* in_sizes, int n_in,
                              void* d_out, int out_size, void* d_ws, size_t ws_size,
                              hipStream_t stream) {
    const float* x         = (const float*)d_in[0];
    const float* thetas    = (const float*)d_in[1];
    const float* positions = (const float*)d_in[2];
    float* out = (float*)d_out;

    hipFuncSetAttribute((const void*)radon_fwd,
                        hipFuncAttributeMaxDynamicSharedMemorySize, SMEM_BYTES);

    // output accumulated via atomics -> zero it first (async, capture-safe)
    hipMemsetAsync(d_out, 0, (size_t)out_size * sizeof(float), stream);

    dim3 grid(NA / GANG, NB, 2);   // 60 x 4 x 2 = 480 blocks
    dim3 block(NP, NSEG);          // 1024 threads
    radon_fwd<<<grid, block, SMEM_BYTES, stream>>>(x, thetas, positions, out);
}

// Round 8
// 108.340 us; speedup vs baseline: 1.1822x; 1.1822x over previous
//
#include <hip/hip_runtime.h>
#include <hip/hip_fp16.h>

// Radon forward: x [4,1,256,256] f32, thetas[180], positions[256] -> out [4,1,180,256] f32
// T=363 samples/ray (we run 364; extras land in the zero border -> +0).
//
// Structure (proven in round 6): half-image per block -> 2 blocks/CU; row-split
// regime A (|cos|>=0.707), col-split regime B; exact t-partition at S computed
// from an identical float expression in both halves; atomicAdd combine.
//
// New in round 7: exact per-ray support clipping. Samples whose bilinear
// support lies outside the image contribute exactly 0 via the clamp+zero-border
// path, so skipping them is safe as long as the interval is OVER-wide; we widen
// by 1 sample each side. ~32% of samples eliminated (sum of chords = area).

#define NB   4
#define NA   180
#define NP   256
#define GANG 3       // angles per block; regime boundaries 45,135 are multiples of 3
#define NSEG 4

// Regime A (row-split): stride 131 dw (262 halves), 132 alloc rows -> 17292 dw
// Regime B (col-split): stride  67 dw (134 halves), 259 alloc rows -> 17353 dw
#define IMG_DW_MAX 17353
#define RED_OFF ((IMG_DW_MAX + 1) * 4)        // 69416 (pad 1 dw: benign tap-read slack)
#define SMEM_BYTES (RED_OFF + NP * NSEG * 4)  // 73512 ; 2 blocks = 147KB <= 160KB/CU

template<int STRIDE_DW>
__device__ __forceinline__ float ray_accum(
    const unsigned int* __restrict__ imgw,
    float bxr, float byr, float nsv, float cv,
    float xlo, float xhi, float ylo, float yhi,
    int tlo, int thi, int seg)
{
    float acc = 0.f;
    int   t  = tlo + seg;
    // incremental unclamped coordinates (error ~1e-4 px over 90 steps: negligible)
    float pxu = fmaf((float)t - 181.0f, nsv, bxr);
    float pyu = fmaf((float)t - 181.0f, cv,  byr);
    const float dpx = 4.0f * nsv;
    const float dpy = 4.0f * cv;
    #pragma unroll 4
    for (; t < thi; t += 4) {
        float px = __builtin_amdgcn_fmed3f(pxu, xlo, xhi);  // clamp into staged+zero region
        float py = __builtin_amdgcn_fmed3f(pyu, ylo, yhi);
        pxu += dpx;
        pyu += dpy;
        const float fx = floorf(px);
        const float fy = floorf(py);
        const float wx = px - fx;
        const float wy = py - fy;
        const int a = (int)fmaf(fy, (float)(2 * STRIDE_DW), fx);  // half-index
        const int kd = a >> 1;
        const unsigned sh = (a & 1) << 4;
        const unsigned d0 = imgw[kd];
        const unsigned d1 = imgw[kd + 1];
        const unsigned d2 = imgw[kd + STRIDE_DW];
        const unsigned d3 = imgw[kd + STRIDE_DW + 1];
        unsigned q0 = (unsigned)(((((unsigned long long)d1) << 32) | d0) >> sh);
        unsigned q1 = (unsigned)(((((unsigned long long)d3) << 32) | d2) >> sh);
        const __half2 h0 = *reinterpret_cast<__half2*>(&q0);   // (v00, v01)
        const __half2 h1 = *reinterpret_cast<__half2*>(&q1);   // (v10, v11)
        // vertical lerp packed in f16, horizontal in f32
        const __half2 dv  = __hsub2(h1, h0);
        const __half2 wy2 = __half2half2(__float2half_rn(wy));
        const __half2 V   = __hfma2(wy2, dv, h0);
        const float vlo = __half2float(__low2half(V));
        const float vhi = __half2float(__high2half(V));
        acc = fmaf(wx, vhi - vlo, acc + vlo);
    }
    return acc;
}

extern "C" __global__ __launch_bounds__(1024)
void radon_fwd(const float* __restrict__ x,
               const float* __restrict__ thetas,
               const float* __restrict__ positions,
               float* __restrict__ out)
{
    extern __shared__ unsigned char smem[];
    unsigned int* imgw = (unsigned int*)smem;
    __half2*      img2 = (__half2*)smem;
    float*        red  = (float*)(smem + RED_OFF);

    const int grp  = blockIdx.x;
    const int b    = blockIdx.y;
    const int half = blockIdx.z;
    const int a0   = grp * GANG;
    const bool regA = (a0 < 45) || (a0 >= 135);
    const int tid = threadIdx.x + (threadIdx.y << 8);
    const float* __restrict__ xb = x + b * 65536;

    // --- zero LDS image area ---
    for (int i = tid; i <= IMG_DW_MAX; i += 1024) imgw[i] = 0u;
    __syncthreads();

    // --- stage half image as f16 (zero border built in) ---
    if (regA) {
        // half0: img rows 0..129 -> lds rows 1..130 ; half1: img rows 126..255 -> lds rows 0..129
        const int rbase  = half ? 126 : 0;
        const int rowoff = half ? 0 : 1;
        const float2* src2 = (const float2*)(xb + rbase * 256);
        for (int j = tid; j < 130 * 128; j += 1024) {
            const int rr = j >> 7;         // 0..129
            const int k  = j & 127;        // float2 index within row (128 per row)
            float2 v = src2[rr * 128 + k];
            img2[(rr + rowoff) * 131 + k + 1] = __floats2half2_rn(v.x, v.y);
        }
    } else {
        // half0: img cols 0..131 -> lds dw cols 1..66 ; half1: img cols 124..255 -> dw cols 0..65
        const int cbase2 = half ? 62 : 0;
        const int coff   = half ? 0 : 1;
        const float2* src2 = (const float2*)xb;
        for (int rr = tid >> 6; rr < 256; rr += 16) {
            for (int c2 = tid & 63; c2 < 66; c2 += 64) {
                float2 v = src2[rr * 128 + cbase2 + c2];
                img2[(rr + 1) * 67 + c2 + coff] = __floats2half2_rn(v.x, v.y);
            }
        }
    }
    __syncthreads();

    // --- per-half clamp bounds (alloc space, rebased) ---
    float xlo, xhi, ylo, yhi;
    if (regA) {
        xlo = 1.f; xhi = 258.f;
        if (half == 0) { ylo = 0.f; yhi = 129.984375f; }
        else           { ylo = 1.f; yhi = 130.f; }
    } else {
        ylo = 0.f; yhi = 257.f;
        if (half == 0) { xlo = 1.f; xhi = 130.984375f; }
        else           { xlo = 3.f; xhi = 132.f; }
    }
    const float rebY = (regA && half) ? 127.f : 0.f;
    const float rebX = (!regA && half) ? 126.f : 0.f;

    const int   p   = threadIdx.x;
    const int   seg = threadIdx.y;
    const float s   = positions[p];

    float accs[GANG];
    for (int g = 0; g < GANG; ++g) {
        const float th  = thetas[a0 + g];
        const float cv  = cosf(th);
        const float sv  = sinf(th);
        const float nsv = -sv;
        const float bx2 = fmaf(s, cv, 129.5f);   // alloc-x base (col offset +2)
        const float by1 = fmaf(s, sv, 128.5f);   // alloc-y base (row offset +1)
        // ownership split -- IDENTICAL float computation in both halves.
        // alloc(t) = base + (t - 181)*slope  =>  t* = 181 + (thr - base)/slope
        const float slope = regA ? cv : nsv;     // |slope| >= 0.707 by regime choice
        const float base  = regA ? by1 : bx2;
        const float thr   = regA ? 129.f : 130.f;
        const float tstar = 181.0f + (thr - base) / slope;
        const float Sf    = (slope > 0.f) ? ceilf(tstar) : (floorf(tstar) + 1.0f);
        const int   S     = (int)fmaxf(0.f, fminf(364.f, Sf));
        const bool  h0Low = (slope > 0.f);       // half0 owns low-t side iff slope>0
        int lo, hi;
        if ((half == 0) == h0Low) { lo = 0; hi = S; }
        else                      { lo = S; hi = 364; }

        // --- exact support clipping (over-wide by 1 each side: provably safe,
        //     skipped samples ride the clamp+zero-border path and contribute 0) ---
        // support: px_alloc in [1,258], py_alloc in [0,257]; u = t-181
        const float msx = (fabsf(sv) < 1e-7f) ? copysignf(1e-7f, sv) : sv;
        const float mcy = (fabsf(cv) < 1e-7f) ? copysignf(1e-7f, cv) : cv;
        const float invx = -1.0f / msx;          // d(px)/dt = -sv
        const float invy =  1.0f / mcy;          // d(py)/dt = +cv
        const float ux1 = (1.0f   - bx2) * invx;
        const float ux2 = (258.0f - bx2) * invx;
        const float uy1 = (0.0f   - by1) * invy;
        const float uy2 = (257.0f - by1) * invy;
        const float ulo = fmaxf(fminf(ux1, ux2), fminf(uy1, uy2));
        const float uhi = fminf(fmaxf(ux1, ux2), fmaxf(uy1, uy2));
        const float tbf = ceilf(ulo + 181.0f) - 1.0f;   // widened begin
        const float tef = floorf(uhi + 181.0f) + 2.0f;  // widened exclusive end
        const int tb = (int)fmaxf((float)lo, fminf(364.0f, tbf));
        const int te = (int)fminf((float)hi, fmaxf(0.0f,  tef));

        const float bxr = bx2 - rebX;
        const float byr = by1 - rebY;
        accs[g] = regA
            ? ray_accum<131>(imgw, bxr, byr, nsv, cv, xlo, xhi, ylo, yhi, tb, te, seg)
            : ray_accum< 67>(imgw, bxr, byr, nsv, cv, xlo, xhi, ylo, yhi, tb, te, seg);
    }

    // --- reduce 4 segs, then one atomicAdd per (g,p) (2 adds/output total) ---
    for (int g = 0; g < GANG; ++g) {
        __syncthreads();
        red[(seg << 8) + p] = accs[g];
        __syncthreads();
        if (seg == 0) {
            float r4 = red[p] + red[256 + p] + red[512 + p] + red[768 + p];
            atomicAdd(&out[b * (NA * NP) + (a0 + g) * NP + p], r4);
        }
    }
}

extern "C" void kernel_launch(void* const* d_in, const int* in_sizes, int n_in,
                              void* d_out, int out_size, void* d_ws, size_t ws_size,
                              hipStream_t stream) {
    const float* x         = (const float*)d_in[0];
    const float* thetas    = (const float*)d_in[1];
    const float* positions = (const float*)d_in[2];
    float* out = (float*)d_out;

    hipFuncSetAttribute((const void*)radon_fwd,
                        hipFuncAttributeMaxDynamicSharedMemorySize, SMEM_BYTES);

    // output accumulated via atomics -> zero it first (async, capture-safe)
    hipMemsetAsync(d_out, 0, (size_t)out_size * sizeof(float), stream);

    dim3 grid(NA / GANG, NB, 2);   // 60 x 4 x 2 = 480 blocks
    dim3 block(NP, NSEG);          // 1024 threads
    radon_fwd<<<grid, block, SMEM_BYTES, stream>>>(x, thetas, positions, out);
}